// Round 14
// baseline (177.624 us; speedup 1.0000x reference)
//
#include <hip/hip_runtime.h>
#include <hip/hip_bf16.h>

// MDN NLL, fully fused. N=524288 Dx=128 Dt=64 M=32 K=8.
// Memory-bound target: 470 MB reads -> ~75us floor at 6.3 TB/s.
// R14 = R13 (142us: column-split 16 waves, transposed MFMA, single lgkm
// barrier/iter, reg-staged bf16 x/t + f32 y, involution swizzle) with
// TILE_R 32->64: one barrier per 64 rows (CU barrier events halve),
// rt loop 2->4, gate+LSE on waves 0-3 over four DISTINCT sample-quarters
// (removes R10/R13 duplicated gate), staging = x on all 1024 threads +
// t on tids 0-511 + y on tids 512-1023 (1 chunk each role).
// Known-structural leftovers: ~41MB prologue spill (20 dwords/thread,
// hard 128-unified cap at 1024 thr); 9.4M bank-conflict counts tracking
// shuffle ds_permutes, layout-insensitive (R11 A/B).

#define NN 524288
#define DX 128
#define DT 64
#define MDIM 32
#define KEXP 8
#define TILE_R 64
#define THREADS 1024
#define GRID_MAIN 512
#define TILES_TOTAL (NN / TILE_R)        // 8192
#define TPB (TILES_TOTAL / GRID_MAIN)    // 16

typedef __bf16 bf16x8 __attribute__((ext_vector_type(8)));
typedef float f32x4 __attribute__((ext_vector_type(4)));

__device__ __forceinline__ bf16x8 cvt8(const f32x4 a, const f32x4 b) {
  bf16x8 r;
  r[0] = (__bf16)a[0]; r[1] = (__bf16)a[1]; r[2] = (__bf16)a[2]; r[3] = (__bf16)a[3];
  r[4] = (__bf16)b[0]; r[5] = (__bf16)b[1]; r[6] = (__bf16)b[2]; r[7] = (__bf16)b[3];
  return r;
}

#define MFMA16(a, b, c) __builtin_amdgcn_mfma_f32_16x16x32_bf16(a, b, c, 0, 0, 0)

// LDS-only barrier: global loads stay in flight across it (rule 18 fence).
#define B_LDS() do { \
  asm volatile("s_waitcnt lgkmcnt(0)" ::: "memory"); \
  __builtin_amdgcn_s_barrier(); \
  __builtin_amdgcn_sched_barrier(0); } while (0)

__global__ __launch_bounds__(THREADS, 4) void mdn_main(
    const float* __restrict__ x, const float* __restrict__ t,
    const float* __restrict__ y, const float* __restrict__ Wm,
    const float* __restrict__ bm, const float* __restrict__ Wv,
    const float* __restrict__ bv, const float* __restrict__ Wg,
    const float* __restrict__ bg, float* __restrict__ partials,
    float* __restrict__ out_atomic)
{
  __shared__ __align__(16) unsigned short xs_l[2][TILE_R * DX];   // bf16 2x16KB
  __shared__ __align__(16) unsigned short ts_l[2][TILE_R * DT];   // bf16 2x8KB
  __shared__ __align__(16) float ys_l[2][TILE_R * MDIM];          // f32 2x8KB
  __shared__ __align__(16) unsigned short wg_lds[2 * 64 * 8];     // 2KB
  __shared__ float llp[2][TILE_R * 20];                           // 10KB dbuf
  __shared__ float red_s[16];

  const int tid = threadIdx.x;
  const int lane = tid & 63;
  const int wv = tid >> 6;        // 0..15
  const int l15 = lane & 15;
  const int lhi = lane >> 4;      // 0..3
  const int kx = wv & 7;          // expert
  const int hh = wv >> 3;         // column half (m-cols hh*16 .. +16)

  // ---- staging roles (involution swizzle: slot s holds global chunk
  // g = s ^ (row&7); readers use the same XOR) ----
  // x: all threads, 64 rows x 16 chunks of 8 floats.
  const int xr = tid >> 4, xsl = tid & 15, xg = xsl ^ (xr & 7);
  const int x_src = xr * DX + xg * 8;            // floats
  const int x_dst = xr * 256 + xsl * 16;         // bytes
  // t: tids 0-511, 64 rows x 8 chunks of 8 floats.
  const int tr = tid >> 3, tsl = tid & 7, tg = tsl ^ (tr & 7);
  const int t_src = tr * DT + tg * 8;
  const int t_dst = tr * 128 + tsl * 16;
  // y: tids 512-1023, 64 rows x 8 chunks of 4 floats.
  const int uy = tid - 512;
  const int yr = uy >> 3, ysl = uy & 7, yg = ysl ^ (yr & 7);
  const int y_src = yr * MDIM + yg * 4;
  const int y_dst = yr * 128 + ysl * 16;

  f32x4 xa, xb, ta, tb, ya;
  auto issue = [&](int tile) {
    const float* xp = x + (size_t)tile * (TILE_R * DX) + x_src;
    xa = *(const f32x4*)xp;
    xb = *(const f32x4*)(xp + 4);
    if (tid < 512) {
      const float* tp = t + (size_t)tile * (TILE_R * DT) + t_src;
      ta = *(const f32x4*)tp;
      tb = *(const f32x4*)(tp + 4);
    } else {
      ya = *(const f32x4*)(y + (size_t)tile * (TILE_R * MDIM) + y_src);
    }
  };
  auto commit = [&](int buf) {
    *(bf16x8*)((char*)xs_l[buf] + x_dst) = cvt8(xa, xb);
    if (tid < 512) *(bf16x8*)((char*)ts_l[buf] + t_dst) = cvt8(ta, tb);
    else           *(f32x4*)((char*)ys_l[buf] + y_dst) = ya;
  };

  const int first = blockIdx.x * TPB;
  issue(first);    // tile-0 loads in flight under the weight prologue

  // biases once, direct from global: lane's 4 m's = hh*16 + lhi*4 + j
  const f32x4 bmean = *(const f32x4*)&bm[kx * MDIM + hh * 16 + lhi * 4];
  const f32x4 blv   = *(const f32x4*)&bv[kx * MDIM + hh * 16 + lhi * 4];
  f32x4 bgv = {0.f, 0.f, 0.f, 0.f};
  if (wv < 4) bgv = *(const f32x4*)&bg[(lhi & 1) * 4];

  // W fragments (A-operand, transposed MFMA): ct 0 = mean, 1 = logvar;
  // cols = hh*16 + l15; k = lhi*8 + i.  8 frags = 32 regs.
  bf16x8 bfrag[2][4];
  #pragma unroll
  for (int ct = 0; ct < 2; ++ct) {
    const float* W = (ct ? Wv : Wm) + (size_t)kx * (DX * MDIM);
    const int mcol = hh * 16 + l15;
    #pragma unroll
    for (int kk = 0; kk < 4; ++kk) {
      bf16x8 tmp;
      #pragma unroll
      for (int i = 0; i < 8; ++i)
        tmp[i] = (__bf16)W[(kk * 32 + lhi * 8 + i) * MDIM + mcol];
      bfrag[ct][kk] = tmp;
    }
  }
  // Gate weights -> LDS (one wave; rows >= KEXP zero-padded)
  if (wv == 15) {
    #pragma unroll
    for (int kk = 0; kk < 2; ++kk) {
      bf16x8 tmp;
      #pragma unroll
      for (int i = 0; i < 8; ++i) {
        const int d = kk * 32 + lhi * 8 + i;
        tmp[i] = (__bf16)((l15 < KEXP) ? Wg[d * KEXP + l15] : 0.f);
      }
      *(bf16x8*)((char*)wg_lds + (kk * 64 + lane) * 16) = tmp;
    }
  }

  commit(0);
  B_LDS();        // tile 0 + wg visible

  float loss_acc = 0.f;
  const float HL2PI = 0.91893853320467274f;   // 0.5*log(2*pi)

  for (int it = 0; it < TPB; ++it) {
    const int cur = it & 1;
    issue(first + ((it + 1 < TPB) ? it + 1 : it));   // next tile, early

    // ---- gate MFMA (waves 0-3, DISTINCT sample-quarters; ts[cur]
    // visible since last barrier) ----
    f32x4 lgv = {0.f, 0.f, 0.f, 0.f};
    if (wv < 4) {
      const int rr = wv * 16 + l15;
      const int r7 = rr & 7;
      f32x4 g = {0.f, 0.f, 0.f, 0.f};
      #pragma unroll
      for (int kk = 0; kk < 2; ++kk) {
        const int s = (kk * 4 + lhi) ^ r7;
        const bf16x8 tf = *(const bf16x8*)((const char*)ts_l[cur] + rr * 128 + s * 16);
        const bf16x8 wf = *(const bf16x8*)((const char*)wg_lds + (kk * 64 + lane) * 16);
        g = MFMA16(wf, tf, g);
      }
      #pragma unroll
      for (int j = 0; j < 4; ++j) lgv[j] = g[j] + bgv[j];
    }

    // ---- expert MFMAs + half-column Gaussian-LL (4 sample-quarters) ----
    const unsigned short* xc = xs_l[cur];
    const float* yc = ys_l[cur];
    #pragma unroll
    for (int rt = 0; rt < 4; ++rt) {
      const int rr = rt * 16 + l15;     // sample (B-col = l15)
      const int r7 = rr & 7;
      f32x4 acc0 = bmean, acc1 = blv;
      #pragma unroll
      for (int kk = 0; kk < 4; ++kk) {
        const int s = (kk * 4 + lhi) ^ r7;
        const bf16x8 af = *(const bf16x8*)((const char*)xc + rr * 256 + s * 16);
        acc0 = MFMA16(bfrag[0][kk], af, acc0);
        acc1 = MFMA16(bfrag[1][kk], af, acc1);
      }
      // D: col = l15 = sample, row = lhi*4+j = m (within half hh)
      const int sy = (hh * 4 + lhi) ^ r7;
      const f32x4 y4 = *(const f32x4*)&yc[rr * 32 + sy * 4];
      float part = 0.f;
      #pragma unroll
      for (int j = 0; j < 4; ++j) {
        const float d = y4[j] - acc0[j];
        part += d * d * (0.5f * __expf(-acc1[j])) + 0.5f * acc1[j];
      }
      part += __shfl_xor(part, 16);
      part += __shfl_xor(part, 32);
      if (lhi == 0) llp[cur][rr * 20 + hh * 8 + kx] = -(part + 16.0f * HL2PI);
    }

    commit(cur ^ 1);   // write next tile into the other buffers
    B_LDS();           // the ONE barrier: llp[cur] + staged buffers visible

    // ---- LSE over experts (waves 0-3, distinct quarters): in-lane over
    // 4 k's + 1 shfl. Waves 4-15 fall through to the next iteration. ----
    if (wv < 4) {
      const int rr = wv * 16 + l15;
      const f32x4 lvA = *(const f32x4*)&llp[cur][rr * 20 + (lhi & 1) * 4];
      const f32x4 lvB = *(const f32x4*)&llp[cur][rr * 20 + 8 + (lhi & 1) * 4];
      f32x4 a4;
      #pragma unroll
      for (int j = 0; j < 4; ++j) a4[j] = lgv[j] + lvA[j] + lvB[j];
      float mg = fmaxf(fmaxf(lgv[0], lgv[1]), fmaxf(lgv[2], lgv[3]));
      float ma = fmaxf(fmaxf(a4[0], a4[1]), fmaxf(a4[2], a4[3]));
      mg = fmaxf(mg, __shfl_xor(mg, 16));
      ma = fmaxf(ma, __shfl_xor(ma, 16));
      float eg = __expf(lgv[0] - mg) + __expf(lgv[1] - mg)
               + __expf(lgv[2] - mg) + __expf(lgv[3] - mg);
      float ea = __expf(a4[0] - ma) + __expf(a4[1] - ma)
               + __expf(a4[2] - ma) + __expf(a4[3] - ma);
      eg += __shfl_xor(eg, 16);
      ea += __shfl_xor(ea, 16);
      if (lhi == 0)
        loss_acc += (mg + __logf(eg)) - (ma + __logf(ea));
    }
  }

  // block reduction of loss
  loss_acc += __shfl_xor(loss_acc, 1);
  loss_acc += __shfl_xor(loss_acc, 2);
  loss_acc += __shfl_xor(loss_acc, 4);
  loss_acc += __shfl_xor(loss_acc, 8);
  loss_acc += __shfl_xor(loss_acc, 16);
  loss_acc += __shfl_xor(loss_acc, 32);
  if (lane == 0) red_s[wv] = loss_acc;
  __syncthreads();
  if (tid == 0) {
    float s = 0.f;
    #pragma unroll
    for (int w = 0; w < 16; ++w) s += red_s[w];
    if (partials) partials[blockIdx.x] = s;
    else atomicAdd(out_atomic, s);
  }
}

__global__ void mdn_reg(const float* __restrict__ Wm, const float* __restrict__ Wv,
                        const float* __restrict__ Wg, float* __restrict__ partials,
                        float* __restrict__ out_atomic)
{
  __shared__ float red[4];
  const int gid = blockIdx.x * 256 + threadIdx.x;
  const int stride = 64 * 256;
  float s = 0.f;
  for (int i = gid; i < DX * MDIM * KEXP; i += stride) { float w = Wm[i]; s += w * w; }
  for (int i = gid; i < DX * MDIM * KEXP; i += stride) { float w = Wv[i]; s += w * w; }
  for (int i = gid; i < DT * KEXP; i += stride)        { float w = Wg[i]; s += w * w; }
  s += __shfl_xor(s, 1);
  s += __shfl_xor(s, 2);
  s += __shfl_xor(s, 4);
  s += __shfl_xor(s, 8);
  s += __shfl_xor(s, 16);
  s += __shfl_xor(s, 32);
  if ((threadIdx.x & 63) == 0) red[threadIdx.x >> 6] = s;
  __syncthreads();
  if (threadIdx.x == 0) {
    float b = red[0] + red[1] + red[2] + red[3];
    if (partials) partials[GRID_MAIN + blockIdx.x] = b;
    else atomicAdd(out_atomic, b);
  }
}

__global__ void mdn_final(const float* __restrict__ partials, float* __restrict__ out)
{
  __shared__ float red[4];
  float s = 0.f;
  for (int i = threadIdx.x; i < GRID_MAIN + 64; i += 256) s += partials[i];
  s += __shfl_xor(s, 1);
  s += __shfl_xor(s, 2);
  s += __shfl_xor(s, 4);
  s += __shfl_xor(s, 8);
  s += __shfl_xor(s, 16);
  s += __shfl_xor(s, 32);
  if ((threadIdx.x & 63) == 0) red[threadIdx.x >> 6] = s;
  __syncthreads();
  if (threadIdx.x == 0) out[0] = red[0] + red[1] + red[2] + red[3];
}

extern "C" void kernel_launch(void* const* d_in, const int* in_sizes, int n_in,
                              void* d_out, int out_size, void* d_ws, size_t ws_size,
                              hipStream_t stream)
{
  const float* x  = (const float*)d_in[0];
  const float* t  = (const float*)d_in[1];
  const float* y  = (const float*)d_in[2];
  const float* Wm = (const float*)d_in[3];
  const float* bm = (const float*)d_in[4];
  const float* Wv = (const float*)d_in[5];
  const float* bv = (const float*)d_in[6];
  const float* Wg = (const float*)d_in[7];
  const float* bg = (const float*)d_in[8];
  float* out = (float*)d_out;

  if (ws_size >= (GRID_MAIN + 64) * sizeof(float)) {
    float* partials = (float*)d_ws;
    mdn_main<<<GRID_MAIN, THREADS, 0, stream>>>(x, t, y, Wm, bm, Wv, bv, Wg, bg,
                                                partials, nullptr);
    mdn_reg<<<64, 256, 0, stream>>>(Wm, Wv, Wg, partials, nullptr);
    mdn_final<<<1, 256, 0, stream>>>(partials, out);
  } else {
    hipMemsetAsync(out, 0, sizeof(float), stream);
    mdn_main<<<GRID_MAIN, THREADS, 0, stream>>>(x, t, y, Wm, bm, Wv, bv, Wg, bg,
                                                nullptr, out);
    mdn_reg<<<64, 256, 0, stream>>>(Wm, Wv, Wg, nullptr, out);
  }
}

// Round 15
// 138.884 us; speedup vs baseline: 1.2789x; 1.2789x over previous
//
#include <hip/hip_runtime.h>
#include <hip/hip_bf16.h>

// MDN NLL, fully fused. N=524288 Dx=128 Dt=64 M=32 K=8.
// Memory-bound target: 470 MB reads -> ~75us floor at 6.3 TB/s.
// R15 = R13 (142us best) + register-neutral critical-path fixes:
//  - gate dedup: waves 0-1 only (R13 ran it on 0-3, half wasted).
//  - deferred LSE: gate stores logit+bg to glog[2] LDS; LSE for iter i
//    runs at TOP of iter i+1 on waves 4-5 (disjoint from gate waves),
//    overlapping the next tile's MFMAs. Post-barrier tail eliminated.
//    WAR: glog/llp[b] read in i+1 region A < barrier(i+1) < write in i+2.
// R13 carried: column-split 16 waves (kx=wv&7, hh=wv>>3), bfrag=32 regs,
//   transposed MFMA, single lgkm barrier/iter, reg-staged bf16 x/t + f32 y,
//   involution swizzle.
// R14 lesson: TILE_R=64 staging regs -> 148MB spill at the hard 128-reg
//   cap (1024 thr). Any change must be register-neutral.

#define NN 524288
#define DX 128
#define DT 64
#define MDIM 32
#define KEXP 8
#define TILE_R 32
#define THREADS 1024
#define GRID_MAIN 512
#define TILES_TOTAL (NN / TILE_R)        // 16384
#define TPB (TILES_TOTAL / GRID_MAIN)    // 32

typedef __bf16 bf16x8 __attribute__((ext_vector_type(8)));
typedef float f32x4 __attribute__((ext_vector_type(4)));

__device__ __forceinline__ bf16x8 cvt8(const f32x4 a, const f32x4 b) {
  bf16x8 r;
  r[0] = (__bf16)a[0]; r[1] = (__bf16)a[1]; r[2] = (__bf16)a[2]; r[3] = (__bf16)a[3];
  r[4] = (__bf16)b[0]; r[5] = (__bf16)b[1]; r[6] = (__bf16)b[2]; r[7] = (__bf16)b[3];
  return r;
}

#define MFMA16(a, b, c) __builtin_amdgcn_mfma_f32_16x16x32_bf16(a, b, c, 0, 0, 0)

// LDS-only barrier: global loads stay in flight across it (rule 18 fence).
#define B_LDS() do { \
  asm volatile("s_waitcnt lgkmcnt(0)" ::: "memory"); \
  __builtin_amdgcn_s_barrier(); \
  __builtin_amdgcn_sched_barrier(0); } while (0)

__global__ __launch_bounds__(THREADS, 4) void mdn_main(
    const float* __restrict__ x, const float* __restrict__ t,
    const float* __restrict__ y, const float* __restrict__ Wm,
    const float* __restrict__ bm, const float* __restrict__ Wv,
    const float* __restrict__ bv, const float* __restrict__ Wg,
    const float* __restrict__ bg, float* __restrict__ partials,
    float* __restrict__ out_atomic)
{
  __shared__ __align__(16) unsigned short xs_l[2][TILE_R * DX];   // bf16 2x8KB
  __shared__ __align__(16) unsigned short ts_l[2][TILE_R * DT];   // bf16 2x4KB
  __shared__ __align__(16) float ys_l[2][TILE_R * MDIM];          // f32 2x4KB
  __shared__ __align__(16) unsigned short wg_lds[2 * 64 * 8];     // 2KB
  __shared__ float llp[2][TILE_R * 20];                           // 5KB dbuf
  __shared__ __align__(16) float glog[2][TILE_R * 8];             // 2KB dbuf
  __shared__ float red_s[16];

  const int tid = threadIdx.x;
  const int lane = tid & 63;
  const int wv = tid >> 6;        // 0..15
  const int l15 = lane & 15;
  const int lhi = lane >> 4;      // 0..3
  const int kx = wv & 7;          // expert
  const int hh = wv >> 3;         // column half (m-cols hh*16 .. +16)

  // ---- staging role geometry (involution swizzle: slot s holds global
  // chunk g = s ^ (row&7); readers use the same XOR) ----
  int st_ldsoff;                  // byte offset within destination buffer
  const float* st_base;
  int st_stride;                  // floats per tile
  if (tid < 512) {                // x: 32 rows x 16 chunks (16B bf16 out)
    const int r = tid >> 4, s = tid & 15, g = s ^ (r & 7);
    st_base = x + (size_t)r * DX + g * 8;
    st_stride = TILE_R * DX;
    st_ldsoff = r * 256 + s * 16;
  } else if (tid < 768) {         // t: 32 rows x 8 chunks
    const int u = tid - 512, r = u >> 3, s = u & 7, g = s ^ (r & 7);
    st_base = t + (size_t)r * DT + g * 8;
    st_stride = TILE_R * DT;
    st_ldsoff = r * 128 + s * 16;
  } else {                        // y: 32 rows x 8 chunks (f32x4 out)
    const int u = tid - 768, r = u >> 3, s = u & 7, g = s ^ (r & 7);
    st_base = y + (size_t)r * MDIM + g * 4;
    st_stride = TILE_R * MDIM;
    st_ldsoff = r * 128 + s * 16;
  }

  f32x4 sa, sb;
  auto issue = [&](int tile) {
    const float* p = st_base + (size_t)tile * st_stride;
    sa = *(const f32x4*)p;
    if (tid < 768) sb = *(const f32x4*)(p + 4);
  };
  auto commit = [&](int buf) {
    if (tid < 512)      *(bf16x8*)((char*)xs_l[buf] + st_ldsoff) = cvt8(sa, sb);
    else if (tid < 768) *(bf16x8*)((char*)ts_l[buf] + st_ldsoff) = cvt8(sa, sb);
    else                *(f32x4*)((char*)ys_l[buf] + st_ldsoff) = sa;
  };

  const int first = blockIdx.x * TPB;
  issue(first);    // tile-0 loads in flight under the weight prologue

  // biases once, direct from global: lane's 4 m's = hh*16 + lhi*4 + j
  const f32x4 bmean = *(const f32x4*)&bm[kx * MDIM + hh * 16 + lhi * 4];
  const f32x4 blv   = *(const f32x4*)&bv[kx * MDIM + hh * 16 + lhi * 4];
  f32x4 bgv = {0.f, 0.f, 0.f, 0.f};
  if (wv < 2) bgv = *(const f32x4*)&bg[(lhi & 1) * 4];

  // W fragments (A-operand, transposed MFMA): ct 0 = mean, 1 = logvar;
  // cols = hh*16 + l15; k = lhi*8 + i.  8 frags = 32 regs.
  bf16x8 bfrag[2][4];
  #pragma unroll
  for (int ct = 0; ct < 2; ++ct) {
    const float* W = (ct ? Wv : Wm) + (size_t)kx * (DX * MDIM);
    const int mcol = hh * 16 + l15;
    #pragma unroll
    for (int kk = 0; kk < 4; ++kk) {
      bf16x8 tmp;
      #pragma unroll
      for (int i = 0; i < 8; ++i)
        tmp[i] = (__bf16)W[(kk * 32 + lhi * 8 + i) * MDIM + mcol];
      bfrag[ct][kk] = tmp;
    }
  }
  // Gate weights -> LDS (one wave; rows >= KEXP zero-padded)
  if (wv == 15) {
    #pragma unroll
    for (int kk = 0; kk < 2; ++kk) {
      bf16x8 tmp;
      #pragma unroll
      for (int i = 0; i < 8; ++i) {
        const int d = kk * 32 + lhi * 8 + i;
        tmp[i] = (__bf16)((l15 < KEXP) ? Wg[d * KEXP + l15] : 0.f);
      }
      *(bf16x8*)((char*)wg_lds + (kk * 64 + lane) * 16) = tmp;
    }
  }

  commit(0);
  B_LDS();        // tile 0 + wg visible

  float loss_acc = 0.f;
  const float HL2PI = 0.91893853320467274f;   // 0.5*log(2*pi)

  for (int it = 0; it < TPB; ++it) {
    const int cur = it & 1;
    issue(first + ((it + 1 < TPB) ? it + 1 : it));   // next tile, early

    // ---- deferred LSE for iter it-1 (waves 4-5; reads llp/glog[cur^1],
    // visible since barrier(it-1); overlaps this iter's MFMAs) ----
    if (it && (wv == 4 || wv == 5)) {
      const int pb = cur ^ 1;
      const int rr = (wv - 4) * 16 + l15;
      const f32x4 lgv = *(const f32x4*)&glog[pb][rr * 8 + (lhi & 1) * 4];
      const f32x4 lvA = *(const f32x4*)&llp[pb][rr * 20 + (lhi & 1) * 4];
      const f32x4 lvB = *(const f32x4*)&llp[pb][rr * 20 + 8 + (lhi & 1) * 4];
      f32x4 a4;
      #pragma unroll
      for (int j = 0; j < 4; ++j) a4[j] = lgv[j] + lvA[j] + lvB[j];
      float mg = fmaxf(fmaxf(lgv[0], lgv[1]), fmaxf(lgv[2], lgv[3]));
      float ma = fmaxf(fmaxf(a4[0], a4[1]), fmaxf(a4[2], a4[3]));
      mg = fmaxf(mg, __shfl_xor(mg, 16));
      ma = fmaxf(ma, __shfl_xor(ma, 16));
      float eg = __expf(lgv[0] - mg) + __expf(lgv[1] - mg)
               + __expf(lgv[2] - mg) + __expf(lgv[3] - mg);
      float ea = __expf(a4[0] - ma) + __expf(a4[1] - ma)
               + __expf(a4[2] - ma) + __expf(a4[3] - ma);
      eg += __shfl_xor(eg, 16);
      ea += __shfl_xor(ea, 16);
      if (lhi == 0)
        loss_acc += (mg + __logf(eg)) - (ma + __logf(ea));
    }

    // ---- gate MFMA (waves 0-1, one per sample-half; ts[cur] visible
    // since last barrier; result -> glog[cur]) ----
    if (wv < 2) {
      const int rr = wv * 16 + l15;
      const int r7 = rr & 7;
      f32x4 g = {0.f, 0.f, 0.f, 0.f};
      #pragma unroll
      for (int kk = 0; kk < 2; ++kk) {
        const int s = (kk * 4 + lhi) ^ r7;
        const bf16x8 tf = *(const bf16x8*)((const char*)ts_l[cur] + rr * 128 + s * 16);
        const bf16x8 wf = *(const bf16x8*)((const char*)wg_lds + (kk * 64 + lane) * 16);
        g = MFMA16(wf, tf, g);
      }
      if (lhi < 2) {
        f32x4 lg;
        #pragma unroll
        for (int j = 0; j < 4; ++j) lg[j] = g[j] + bgv[j];
        *(f32x4*)&glog[cur][rr * 8 + lhi * 4] = lg;
      }
    }

    // ---- expert MFMAs + half-column Gaussian-LL ----
    const unsigned short* xc = xs_l[cur];
    const float* yc = ys_l[cur];
    #pragma unroll
    for (int rt = 0; rt < 2; ++rt) {
      const int rr = rt * 16 + l15;     // sample (B-col = l15)
      const int r7 = rr & 7;
      f32x4 acc0 = bmean, acc1 = blv;
      #pragma unroll
      for (int kk = 0; kk < 4; ++kk) {
        const int s = (kk * 4 + lhi) ^ r7;
        const bf16x8 af = *(const bf16x8*)((const char*)xc + rr * 256 + s * 16);
        acc0 = MFMA16(bfrag[0][kk], af, acc0);
        acc1 = MFMA16(bfrag[1][kk], af, acc1);
      }
      // D: col = l15 = sample, row = lhi*4+j = m (within half hh)
      const int sy = (hh * 4 + lhi) ^ r7;
      const f32x4 y4 = *(const f32x4*)&yc[rr * 32 + sy * 4];
      float part = 0.f;
      #pragma unroll
      for (int j = 0; j < 4; ++j) {
        const float d = y4[j] - acc0[j];
        part += d * d * (0.5f * __expf(-acc1[j])) + 0.5f * acc1[j];
      }
      part += __shfl_xor(part, 16);
      part += __shfl_xor(part, 32);
      if (lhi == 0) llp[cur][rr * 20 + hh * 8 + kx] = -(part + 16.0f * HL2PI);
    }

    commit(cur ^ 1);   // write next tile into the other buffers
    B_LDS();           // the ONE barrier: llp/glog[cur] + staged buffers visible
  }

  // ---- epilogue LSE for the last iteration ----
  {
    const int pb = (TPB - 1) & 1;
    if (wv == 4 || wv == 5) {
      const int rr = (wv - 4) * 16 + l15;
      const f32x4 lgv = *(const f32x4*)&glog[pb][rr * 8 + (lhi & 1) * 4];
      const f32x4 lvA = *(const f32x4*)&llp[pb][rr * 20 + (lhi & 1) * 4];
      const f32x4 lvB = *(const f32x4*)&llp[pb][rr * 20 + 8 + (lhi & 1) * 4];
      f32x4 a4;
      #pragma unroll
      for (int j = 0; j < 4; ++j) a4[j] = lgv[j] + lvA[j] + lvB[j];
      float mg = fmaxf(fmaxf(lgv[0], lgv[1]), fmaxf(lgv[2], lgv[3]));
      float ma = fmaxf(fmaxf(a4[0], a4[1]), fmaxf(a4[2], a4[3]));
      mg = fmaxf(mg, __shfl_xor(mg, 16));
      ma = fmaxf(ma, __shfl_xor(ma, 16));
      float eg = __expf(lgv[0] - mg) + __expf(lgv[1] - mg)
               + __expf(lgv[2] - mg) + __expf(lgv[3] - mg);
      float ea = __expf(a4[0] - ma) + __expf(a4[1] - ma)
               + __expf(a4[2] - ma) + __expf(a4[3] - ma);
      eg += __shfl_xor(eg, 16);
      ea += __shfl_xor(ea, 16);
      if (lhi == 0)
        loss_acc += (mg + __logf(eg)) - (ma + __logf(ea));
    }
  }

  // block reduction of loss
  loss_acc += __shfl_xor(loss_acc, 1);
  loss_acc += __shfl_xor(loss_acc, 2);
  loss_acc += __shfl_xor(loss_acc, 4);
  loss_acc += __shfl_xor(loss_acc, 8);
  loss_acc += __shfl_xor(loss_acc, 16);
  loss_acc += __shfl_xor(loss_acc, 32);
  if (lane == 0) red_s[wv] = loss_acc;
  __syncthreads();
  if (tid == 0) {
    float s = 0.f;
    #pragma unroll
    for (int w = 0; w < 16; ++w) s += red_s[w];
    if (partials) partials[blockIdx.x] = s;
    else atomicAdd(out_atomic, s);
  }
}

__global__ void mdn_reg(const float* __restrict__ Wm, const float* __restrict__ Wv,
                        const float* __restrict__ Wg, float* __restrict__ partials,
                        float* __restrict__ out_atomic)
{
  __shared__ float red[4];
  const int gid = blockIdx.x * 256 + threadIdx.x;
  const int stride = 64 * 256;
  float s = 0.f;
  for (int i = gid; i < DX * MDIM * KEXP; i += stride) { float w = Wm[i]; s += w * w; }
  for (int i = gid; i < DX * MDIM * KEXP; i += stride) { float w = Wv[i]; s += w * w; }
  for (int i = gid; i < DT * KEXP; i += stride)        { float w = Wg[i]; s += w * w; }
  s += __shfl_xor(s, 1);
  s += __shfl_xor(s, 2);
  s += __shfl_xor(s, 4);
  s += __shfl_xor(s, 8);
  s += __shfl_xor(s, 16);
  s += __shfl_xor(s, 32);
  if ((threadIdx.x & 63) == 0) red[threadIdx.x >> 6] = s;
  __syncthreads();
  if (threadIdx.x == 0) {
    float b = red[0] + red[1] + red[2] + red[3];
    if (partials) partials[GRID_MAIN + blockIdx.x] = b;
    else atomicAdd(out_atomic, b);
  }
}

__global__ void mdn_final(const float* __restrict__ partials, float* __restrict__ out)
{
  __shared__ float red[4];
  float s = 0.f;
  for (int i = threadIdx.x; i < GRID_MAIN + 64; i += 256) s += partials[i];
  s += __shfl_xor(s, 1);
  s += __shfl_xor(s, 2);
  s += __shfl_xor(s, 4);
  s += __shfl_xor(s, 8);
  s += __shfl_xor(s, 16);
  s += __shfl_xor(s, 32);
  if ((threadIdx.x & 63) == 0) red[threadIdx.x >> 6] = s;
  __syncthreads();
  if (threadIdx.x == 0) out[0] = red[0] + red[1] + red[2] + red[3];
}

extern "C" void kernel_launch(void* const* d_in, const int* in_sizes, int n_in,
                              void* d_out, int out_size, void* d_ws, size_t ws_size,
                              hipStream_t stream)
{
  const float* x  = (const float*)d_in[0];
  const float* t  = (const float*)d_in[1];
  const float* y  = (const float*)d_in[2];
  const float* Wm = (const float*)d_in[3];
  const float* bm = (const float*)d_in[4];
  const float* Wv = (const float*)d_in[5];
  const float* bv = (const float*)d_in[6];
  const float* Wg = (const float*)d_in[7];
  const float* bg = (const float*)d_in[8];
  float* out = (float*)d_out;

  if (ws_size >= (GRID_MAIN + 64) * sizeof(float)) {
    float* partials = (float*)d_ws;
    mdn_main<<<GRID_MAIN, THREADS, 0, stream>>>(x, t, y, Wm, bm, Wv, bv, Wg, bg,
                                                partials, nullptr);
    mdn_reg<<<64, 256, 0, stream>>>(Wm, Wv, Wg, partials, nullptr);
    mdn_final<<<1, 256, 0, stream>>>(partials, out);
  } else {
    hipMemsetAsync(out, 0, sizeof(float), stream);
    mdn_main<<<GRID_MAIN, THREADS, 0, stream>>>(x, t, y, Wm, bm, Wv, bv, Wg, bg,
                                                nullptr, out);
    mdn_reg<<<64, 256, 0, stream>>>(Wm, Wv, Wg, nullptr, out);
  }
}

// Round 16
// 137.510 us; speedup vs baseline: 1.2917x; 1.0100x over previous
//
#include <hip/hip_runtime.h>
#include <hip/hip_bf16.h>

// MDN NLL, fully fused. N=524288 Dx=128 Dt=64 M=32 K=8.
// Memory-bound target: 470 MB reads -> ~75us floor at 6.3 TB/s.
// R16 = R15 (138.9us best) + SHUFFLE-FREE expert epilogue:
//  - each lane writes its raw lhi-quadrant partial (sum over 4 j's) to
//    llp4[2][32][68] via one unpredicated ds_write_b32 -- the two serial
//    ~120cy shfl_xor(16/32) ops leave every wave's per-iter critical path.
//  - deferred LSE (waves 4-5, overlapped with next tile's MFMAs) sums the
//    8 partials per (sample, expert): 8x ds_read_b128 + ~30 VALU, on waves
//    that were idle anyway. ll = -(sum8) - 32*HL2PI.
//  - stride 68 floats: write banks (4*rr+c)%32 -> 2-way alias (free, m136).
// R15 carried: column-split 16 waves (kx=wv&7, hh=wv>>3), bfrag=32 regs,
//   transposed MFMA, single lgkm barrier/iter, reg-staged bf16 x/t + f32 y,
//   involution swizzle, gate waves 0-1 -> glog, deferred LSE.
// R15 counter lesson: WRITE_SIZE 35MB = 66B/thread = prologue-only spill;
//   no in-loop spill -> register chasing is a dead end. The lever is the
//   intra-wave serial chain (~3-4k of 6600 cy/iter unaccounted by pipes).

#define NN 524288
#define DX 128
#define DT 64
#define MDIM 32
#define KEXP 8
#define TILE_R 32
#define THREADS 1024
#define GRID_MAIN 512
#define TILES_TOTAL (NN / TILE_R)        // 16384
#define TPB (TILES_TOTAL / GRID_MAIN)    // 32

typedef __bf16 bf16x8 __attribute__((ext_vector_type(8)));
typedef float f32x4 __attribute__((ext_vector_type(4)));

__device__ __forceinline__ bf16x8 cvt8(const f32x4 a, const f32x4 b) {
  bf16x8 r;
  r[0] = (__bf16)a[0]; r[1] = (__bf16)a[1]; r[2] = (__bf16)a[2]; r[3] = (__bf16)a[3];
  r[4] = (__bf16)b[0]; r[5] = (__bf16)b[1]; r[6] = (__bf16)b[2]; r[7] = (__bf16)b[3];
  return r;
}

#define MFMA16(a, b, c) __builtin_amdgcn_mfma_f32_16x16x32_bf16(a, b, c, 0, 0, 0)

// LDS-only barrier: global loads stay in flight across it (rule 18 fence).
#define B_LDS() do { \
  asm volatile("s_waitcnt lgkmcnt(0)" ::: "memory"); \
  __builtin_amdgcn_s_barrier(); \
  __builtin_amdgcn_sched_barrier(0); } while (0)

__global__ __launch_bounds__(THREADS, 4) void mdn_main(
    const float* __restrict__ x, const float* __restrict__ t,
    const float* __restrict__ y, const float* __restrict__ Wm,
    const float* __restrict__ bm, const float* __restrict__ Wv,
    const float* __restrict__ bv, const float* __restrict__ Wg,
    const float* __restrict__ bg, float* __restrict__ partials,
    float* __restrict__ out_atomic)
{
  __shared__ __align__(16) unsigned short xs_l[2][TILE_R * DX];   // bf16 2x8KB
  __shared__ __align__(16) unsigned short ts_l[2][TILE_R * DT];   // bf16 2x4KB
  __shared__ __align__(16) float ys_l[2][TILE_R * MDIM];          // f32 2x4KB
  __shared__ __align__(16) unsigned short wg_lds[2 * 64 * 8];     // 2KB
  __shared__ __align__(16) float llp4[2][TILE_R * 68];            // 17.4KB dbuf
  __shared__ __align__(16) float glog[2][TILE_R * 8];             // 2KB dbuf
  __shared__ float red_s[16];

  const int tid = threadIdx.x;
  const int lane = tid & 63;
  const int wv = tid >> 6;        // 0..15
  const int l15 = lane & 15;
  const int lhi = lane >> 4;      // 0..3
  const int kx = wv & 7;          // expert
  const int hh = wv >> 3;         // column half (m-cols hh*16 .. +16)

  // ---- staging role geometry (involution swizzle: slot s holds global
  // chunk g = s ^ (row&7); readers use the same XOR) ----
  int st_ldsoff;                  // byte offset within destination buffer
  const float* st_base;
  int st_stride;                  // floats per tile
  if (tid < 512) {                // x: 32 rows x 16 chunks (16B bf16 out)
    const int r = tid >> 4, s = tid & 15, g = s ^ (r & 7);
    st_base = x + (size_t)r * DX + g * 8;
    st_stride = TILE_R * DX;
    st_ldsoff = r * 256 + s * 16;
  } else if (tid < 768) {         // t: 32 rows x 8 chunks
    const int u = tid - 512, r = u >> 3, s = u & 7, g = s ^ (r & 7);
    st_base = t + (size_t)r * DT + g * 8;
    st_stride = TILE_R * DT;
    st_ldsoff = r * 128 + s * 16;
  } else {                        // y: 32 rows x 8 chunks (f32x4 out)
    const int u = tid - 768, r = u >> 3, s = u & 7, g = s ^ (r & 7);
    st_base = y + (size_t)r * MDIM + g * 4;
    st_stride = TILE_R * MDIM;
    st_ldsoff = r * 128 + s * 16;
  }

  f32x4 sa, sb;
  auto issue = [&](int tile) {
    const float* p = st_base + (size_t)tile * st_stride;
    sa = *(const f32x4*)p;
    if (tid < 768) sb = *(const f32x4*)(p + 4);
  };
  auto commit = [&](int buf) {
    if (tid < 512)      *(bf16x8*)((char*)xs_l[buf] + st_ldsoff) = cvt8(sa, sb);
    else if (tid < 768) *(bf16x8*)((char*)ts_l[buf] + st_ldsoff) = cvt8(sa, sb);
    else                *(f32x4*)((char*)ys_l[buf] + st_ldsoff) = sa;
  };

  const int first = blockIdx.x * TPB;
  issue(first);    // tile-0 loads in flight under the weight prologue

  // biases once, direct from global: lane's 4 m's = hh*16 + lhi*4 + j
  const f32x4 bmean = *(const f32x4*)&bm[kx * MDIM + hh * 16 + lhi * 4];
  const f32x4 blv   = *(const f32x4*)&bv[kx * MDIM + hh * 16 + lhi * 4];
  f32x4 bgv = {0.f, 0.f, 0.f, 0.f};
  if (wv < 2) bgv = *(const f32x4*)&bg[(lhi & 1) * 4];

  // W fragments (A-operand, transposed MFMA): ct 0 = mean, 1 = logvar;
  // cols = hh*16 + l15; k = lhi*8 + i.  8 frags = 32 regs.
  bf16x8 bfrag[2][4];
  #pragma unroll
  for (int ct = 0; ct < 2; ++ct) {
    const float* W = (ct ? Wv : Wm) + (size_t)kx * (DX * MDIM);
    const int mcol = hh * 16 + l15;
    #pragma unroll
    for (int kk = 0; kk < 4; ++kk) {
      bf16x8 tmp;
      #pragma unroll
      for (int i = 0; i < 8; ++i)
        tmp[i] = (__bf16)W[(kk * 32 + lhi * 8 + i) * MDIM + mcol];
      bfrag[ct][kk] = tmp;
    }
  }
  // Gate weights -> LDS (one wave; rows >= KEXP zero-padded)
  if (wv == 15) {
    #pragma unroll
    for (int kk = 0; kk < 2; ++kk) {
      bf16x8 tmp;
      #pragma unroll
      for (int i = 0; i < 8; ++i) {
        const int d = kk * 32 + lhi * 8 + i;
        tmp[i] = (__bf16)((l15 < KEXP) ? Wg[d * KEXP + l15] : 0.f);
      }
      *(bf16x8*)((char*)wg_lds + (kk * 64 + lane) * 16) = tmp;
    }
  }

  commit(0);
  B_LDS();        // tile 0 + wg visible

  float loss_acc = 0.f;
  const float HL2PI = 0.91893853320467274f;   // 0.5*log(2*pi)

  auto do_lse = [&](int pb) {   // waves 4-5; reads llp4/glog[pb]
    const int rr = (wv - 4) * 16 + l15;
    const f32x4 lgv = *(const f32x4*)&glog[pb][rr * 8 + (lhi & 1) * 4];
    const int kb = (lhi & 1) * 4;
    f32x4 a4;
    #pragma unroll
    for (int j = 0; j < 4; ++j) {
      const f32x4 pA = *(const f32x4*)&llp4[pb][rr * 68 + (kb + j) * 4];
      const f32x4 pB = *(const f32x4*)&llp4[pb][rr * 68 + 32 + (kb + j) * 4];
      const float s8 = pA[0] + pA[1] + pA[2] + pA[3]
                     + pB[0] + pB[1] + pB[2] + pB[3];
      a4[j] = lgv[j] - s8 - 32.0f * HL2PI;
    }
    float mg = fmaxf(fmaxf(lgv[0], lgv[1]), fmaxf(lgv[2], lgv[3]));
    float ma = fmaxf(fmaxf(a4[0], a4[1]), fmaxf(a4[2], a4[3]));
    mg = fmaxf(mg, __shfl_xor(mg, 16));
    ma = fmaxf(ma, __shfl_xor(ma, 16));
    float eg = __expf(lgv[0] - mg) + __expf(lgv[1] - mg)
             + __expf(lgv[2] - mg) + __expf(lgv[3] - mg);
    float ea = __expf(a4[0] - ma) + __expf(a4[1] - ma)
             + __expf(a4[2] - ma) + __expf(a4[3] - ma);
    eg += __shfl_xor(eg, 16);
    ea += __shfl_xor(ea, 16);
    if (lhi == 0)
      loss_acc += (mg + __logf(eg)) - (ma + __logf(ea));
  };

  for (int it = 0; it < TPB; ++it) {
    const int cur = it & 1;
    issue(first + ((it + 1 < TPB) ? it + 1 : it));   // next tile, early

    // ---- deferred LSE for iter it-1 (waves 4-5; reads llp4/glog[cur^1],
    // visible since barrier(it-1); overlaps this iter's MFMAs) ----
    if (it && (wv == 4 || wv == 5)) do_lse(cur ^ 1);

    // ---- gate MFMA (waves 0-1, one per sample-half; ts[cur] visible
    // since last barrier; result -> glog[cur]) ----
    if (wv < 2) {
      const int rr = wv * 16 + l15;
      const int r7 = rr & 7;
      f32x4 g = {0.f, 0.f, 0.f, 0.f};
      #pragma unroll
      for (int kk = 0; kk < 2; ++kk) {
        const int s = (kk * 4 + lhi) ^ r7;
        const bf16x8 tf = *(const bf16x8*)((const char*)ts_l[cur] + rr * 128 + s * 16);
        const bf16x8 wf = *(const bf16x8*)((const char*)wg_lds + (kk * 64 + lane) * 16);
        g = MFMA16(wf, tf, g);
      }
      if (lhi < 2) {
        f32x4 lg;
        #pragma unroll
        for (int j = 0; j < 4; ++j) lg[j] = g[j] + bgv[j];
        *(f32x4*)&glog[cur][rr * 8 + lhi * 4] = lg;
      }
    }

    // ---- expert MFMAs + shuffle-free Gaussian-LL partials ----
    const unsigned short* xc = xs_l[cur];
    const float* yc = ys_l[cur];
    #pragma unroll
    for (int rt = 0; rt < 2; ++rt) {
      const int rr = rt * 16 + l15;     // sample (B-col = l15)
      const int r7 = rr & 7;
      f32x4 acc0 = bmean, acc1 = blv;
      #pragma unroll
      for (int kk = 0; kk < 4; ++kk) {
        const int s = (kk * 4 + lhi) ^ r7;
        const bf16x8 af = *(const bf16x8*)((const char*)xc + rr * 256 + s * 16);
        acc0 = MFMA16(bfrag[0][kk], af, acc0);
        acc1 = MFMA16(bfrag[1][kk], af, acc1);
      }
      // D: col = l15 = sample, row = lhi*4+j = m (within half hh)
      const int sy = (hh * 4 + lhi) ^ r7;
      const f32x4 y4 = *(const f32x4*)&yc[rr * 32 + sy * 4];
      float part = 0.f;
      #pragma unroll
      for (int j = 0; j < 4; ++j) {
        const float d = y4[j] - acc0[j];
        part += d * d * (0.5f * __expf(-acc1[j])) + 0.5f * acc1[j];
      }
      // raw quadrant partial -> LDS; no shuffles. LSE sums the 8 later.
      llp4[cur][rr * 68 + hh * 32 + kx * 4 + lhi] = part;
    }

    commit(cur ^ 1);   // write next tile into the other buffers
    B_LDS();           // the ONE barrier: llp4/glog[cur] + staged buffers visible
  }

  // ---- epilogue LSE for the last iteration ----
  if (wv == 4 || wv == 5) do_lse((TPB - 1) & 1);

  // block reduction of loss
  loss_acc += __shfl_xor(loss_acc, 1);
  loss_acc += __shfl_xor(loss_acc, 2);
  loss_acc += __shfl_xor(loss_acc, 4);
  loss_acc += __shfl_xor(loss_acc, 8);
  loss_acc += __shfl_xor(loss_acc, 16);
  loss_acc += __shfl_xor(loss_acc, 32);
  if (lane == 0) red_s[wv] = loss_acc;
  __syncthreads();
  if (tid == 0) {
    float s = 0.f;
    #pragma unroll
    for (int w = 0; w < 16; ++w) s += red_s[w];
    if (partials) partials[blockIdx.x] = s;
    else atomicAdd(out_atomic, s);
  }
}

__global__ void mdn_reg(const float* __restrict__ Wm, const float* __restrict__ Wv,
                        const float* __restrict__ Wg, float* __restrict__ partials,
                        float* __restrict__ out_atomic)
{
  __shared__ float red[4];
  const int gid = blockIdx.x * 256 + threadIdx.x;
  const int stride = 64 * 256;
  float s = 0.f;
  for (int i = gid; i < DX * MDIM * KEXP; i += stride) { float w = Wm[i]; s += w * w; }
  for (int i = gid; i < DX * MDIM * KEXP; i += stride) { float w = Wv[i]; s += w * w; }
  for (int i = gid; i < DT * KEXP; i += stride)        { float w = Wg[i]; s += w * w; }
  s += __shfl_xor(s, 1);
  s += __shfl_xor(s, 2);
  s += __shfl_xor(s, 4);
  s += __shfl_xor(s, 8);
  s += __shfl_xor(s, 16);
  s += __shfl_xor(s, 32);
  if ((threadIdx.x & 63) == 0) red[threadIdx.x >> 6] = s;
  __syncthreads();
  if (threadIdx.x == 0) {
    float b = red[0] + red[1] + red[2] + red[3];
    if (partials) partials[GRID_MAIN + blockIdx.x] = b;
    else atomicAdd(out_atomic, b);
  }
}

__global__ void mdn_final(const float* __restrict__ partials, float* __restrict__ out)
{
  __shared__ float red[4];
  float s = 0.f;
  for (int i = threadIdx.x; i < GRID_MAIN + 64; i += 256) s += partials[i];
  s += __shfl_xor(s, 1);
  s += __shfl_xor(s, 2);
  s += __shfl_xor(s, 4);
  s += __shfl_xor(s, 8);
  s += __shfl_xor(s, 16);
  s += __shfl_xor(s, 32);
  if ((threadIdx.x & 63) == 0) red[threadIdx.x >> 6] = s;
  __syncthreads();
  if (threadIdx.x == 0) out[0] = red[0] + red[1] + red[2] + red[3];
}

extern "C" void kernel_launch(void* const* d_in, const int* in_sizes, int n_in,
                              void* d_out, int out_size, void* d_ws, size_t ws_size,
                              hipStream_t stream)
{
  const float* x  = (const float*)d_in[0];
  const float* t  = (const float*)d_in[1];
  const float* y  = (const float*)d_in[2];
  const float* Wm = (const float*)d_in[3];
  const float* bm = (const float*)d_in[4];
  const float* Wv = (const float*)d_in[5];
  const float* bv = (const float*)d_in[6];
  const float* Wg = (const float*)d_in[7];
  const float* bg = (const float*)d_in[8];
  float* out = (float*)d_out;

  if (ws_size >= (GRID_MAIN + 64) * sizeof(float)) {
    float* partials = (float*)d_ws;
    mdn_main<<<GRID_MAIN, THREADS, 0, stream>>>(x, t, y, Wm, bm, Wv, bv, Wg, bg,
                                                partials, nullptr);
    mdn_reg<<<64, 256, 0, stream>>>(Wm, Wv, Wg, partials, nullptr);
    mdn_final<<<1, 256, 0, stream>>>(partials, out);
  } else {
    hipMemsetAsync(out, 0, sizeof(float), stream);
    mdn_main<<<GRID_MAIN, THREADS, 0, stream>>>(x, t, y, Wm, bm, Wv, bv, Wg, bg,
                                                nullptr, out);
    mdn_reg<<<64, 256, 0, stream>>>(Wm, Wv, Wg, nullptr, out);
  }
}